// Round 21
// baseline (43.099 us; speedup 1.0000x reference)
//
#include <hip/hip_runtime.h>

#define NBINS 256
#define EPSF 1e-12f

typedef float v4f __attribute__((ext_vector_type(4)));

// R21 = R17/R20 with __syncthreads replaced by LDS flag-count sync.
// 512 blocks x 256 threads, block = one (n,c) slice, wave w owns tile
// COLUMN w (4 tiles, register-double-buffered). After PROCESS s, lane0
// publishes ent_s entry + bumps rdy[s]; WR phases spin on rdy[s]>=4.
// Unlike s_barrier (which the compiler precedes with s_waitcnt vmcnt(0),
// draining ALL in-flight loads+stores at every phase boundary), flag spins
// only wait on LDS -> prefetched loads stay in flight across phase
// boundaries and fast waves' stores overlap slow waves' loads.
// Plain stores (R10), cheap fma binning (R8), wave-private hist (R5),
// {96,64,96} write chunks (R17).
__global__ __launch_bounds__(256, 2) void fused_kernel(const float* __restrict__ x,
                                                       float* __restrict__ out) {
    const int nc   = blockIdx.x;              // 0..511
    const int t    = threadIdx.x;
    const int lane = t & 63;
    const int wave = t >> 6;                  // tile COLUMN

    __shared__ unsigned int hist[4][NBINS];   // 4 KB, wave-private
    __shared__ float ent_s[16];               // 4x4 entropy map, row-major
    __shared__ unsigned int rdy[4];           // per-ent-row completion count

    if (t < 4) rdy[t] = 0u;
    __syncthreads();                          // init only (before any loads)

    const float* cbase = x + ((size_t)nc << 16) + (size_t)wave * 64;
    unsigned int* h = hist[wave];

    v4f va[16], vb[16];

#define ISSUE(buf, s)                                                             \
    _Pragma("unroll")                                                             \
    for (int k = 0; k < 16; ++k) {                                                \
        const int f = lane + (k << 6);        /* float4 idx 0..1023 */            \
        buf[k] = *reinterpret_cast<const v4f*>(                                   \
            cbase + (size_t)(s) * (64 * 256) + (size_t)(f >> 4) * 256 + (f & 15) * 4); \
    }

#define PROCESS(buf, s)                                                           \
    {                                                                             \
        float lmin = INFINITY, lmax = -INFINITY;                                  \
        _Pragma("unroll")                                                         \
        for (int k = 0; k < 16; ++k) {                                            \
            lmin = fminf(lmin, fminf(fminf(buf[k].x, buf[k].y),                   \
                                     fminf(buf[k].z, buf[k].w)));                 \
            lmax = fmaxf(lmax, fmaxf(fmaxf(buf[k].x, buf[k].y),                   \
                                     fmaxf(buf[k].z, buf[k].w)));                 \
        }                                                                         \
        _Pragma("unroll")                                                         \
        for (int off = 32; off > 0; off >>= 1) {                                  \
            lmin = fminf(lmin, __shfl_xor(lmin, off));                            \
            lmax = fmaxf(lmax, __shfl_xor(lmax, off));                            \
        }                                                                         \
        uint4 z; z.x = z.y = z.z = z.w = 0u;  /* same-wave DS ops in-order */     \
        reinterpret_cast<uint4*>(h)[lane] = z;                                    \
        const float width = (lmax - lmin) * (1.0f / NBINS);                       \
        const float wsafe = (width > 0.0f) ? width : 1.0f;                        \
        const float inv   = 1.0f / wsafe;                                         \
        const float coff  = -lmin * inv;                                          \
        _Pragma("unroll")                                                         \
        for (int k = 0; k < 16; ++k) {                                            \
            float vals[4] = {buf[k].x, buf[k].y, buf[k].z, buf[k].w};             \
            _Pragma("unroll")                                                     \
            for (int j = 0; j < 4; ++j) {                                         \
                /* arg >= -eps; trunc==floor for >=0, tiny negatives -> 0 */      \
                int bin = (int)fmaf(vals[j], inv, coff);                          \
                bin = min(bin, 255);                                              \
                atomicAdd(&h[bin], 1u);                                           \
            }                                                                     \
        }                                                                         \
        const uint4 c    = reinterpret_cast<const uint4*>(h)[lane];               \
        const float pden = inv * (1.0f / 4096.0f);  /* 1/(4096*wsafe) */          \
        const float p0 = (float)c.x * pden + EPSF;                                \
        const float p1 = (float)c.y * pden + EPSF;                                \
        const float p2 = (float)c.z * pden + EPSF;                                \
        const float p3 = (float)c.w * pden + EPSF;                                \
        float s_ = p0 + p1 + p2 + p3;                                             \
        _Pragma("unroll")                                                         \
        for (int off = 32; off > 0; off >>= 1) s_ += __shfl_xor(s_, off);         \
        const float itot = 1.0f / s_;                                             \
        const float q0 = p0 * itot, q1 = p1 * itot;                               \
        const float q2 = p2 * itot, q3 = p3 * itot;                               \
        float e = q0 * log2f(q0) + q1 * log2f(q1)                                 \
                + q2 * log2f(q2) + q3 * log2f(q3);                                \
        _Pragma("unroll")                                                         \
        for (int off = 32; off > 0; off >>= 1) e += __shfl_xor(e, off);           \
        if (lane == 0) {                                                          \
            ent_s[((s) << 2) + wave] = -e;                                        \
            __threadfence_block();            /* ent visible before flag */       \
            atomicAdd(&rdy[s], 1u);                                               \
        }                                                                         \
    }

#define WAITROW(s)                                                                \
    do {                                                                          \
        while (((volatile unsigned int*)rdy)[s] < 4u) {}                          \
        asm volatile("" ::: "memory");                                            \
    } while (0)

    // ---- horizontal upsample weights (lane = x4), hoisted once ----
    const int x4 = lane;
    const int ix = (int)floorf(((x4 << 2) + 0.5f) * 0.015625f - 0.5f);
    const int x0 = max(ix, 0), x1 = min(ix + 1, 3);
    v4f wv[4];
#pragma unroll
    for (int j = 0; j < 4; ++j) {
        const float fx = ((x4 << 2) + j + 0.5f) * 0.015625f - 0.5f;
        const float wx = fx - floorf(fx);
        const float a  = 1.0f - wx, bb = wx;
        wv[j].x = ((x0 == 0) ? a : 0.0f) + ((x1 == 0) ? bb : 0.0f);
        wv[j].y = ((x0 == 1) ? a : 0.0f) + ((x1 == 1) ? bb : 0.0f);
        wv[j].z = ((x0 == 2) ? a : 0.0f) + ((x1 == 2) ? bb : 0.0f);
        wv[j].w = ((x0 == 3) ? a : 0.0f) + ((x1 == 3) ? bb : 0.0f);
    }
    const v4f* er = reinterpret_cast<const v4f*>(ent_s);   // 4 rows of 4
    v4f* out4 = reinterpret_cast<v4f*>(out) + ((size_t)nc << 14);

    // write nrows/4 rows per wave starting at ystart (wave-strided chunks)
#define WR(ystart, nrows)                                                         \
    _Pragma("unroll")                                                             \
    for (int i = 0; i < (nrows) / 4; ++i) {                                       \
        const int   y   = (ystart) + wave * ((nrows) / 4) + i;                    \
        const float fy  = (y + 0.5f) * 0.015625f - 0.5f;                          \
        const float fiy = floorf(fy);                                             \
        const float wy  = fy - fiy;                                               \
        const int   iy  = (int)fiy;                                               \
        const int   y0  = max(iy, 0), y1 = min(iy + 1, 3);                        \
        const v4f r0 = er[y0];            /* uniform per wave -> broadcast */     \
        const v4f r1 = er[y1];                                                    \
        v4f rv = r0 * (1.0f - wy) + r1 * wy;                                      \
        v4f o;                                                                    \
        o.x = rv.x * wv[0].x + rv.y * wv[0].y + rv.z * wv[0].z + rv.w * wv[0].w;  \
        o.y = rv.x * wv[1].x + rv.y * wv[1].y + rv.z * wv[1].z + rv.w * wv[1].w;  \
        o.z = rv.x * wv[2].x + rv.y * wv[2].y + rv.z * wv[2].z + rv.w * wv[2].w;  \
        o.w = rv.x * wv[3].x + rv.y * wv[3].y + rv.z * wv[3].z + rv.w * wv[3].w;  \
        out4[(y << 6) + lane] = o;                                                \
    }

    // ---- pipelined schedule, flag sync, {96,64,96} write chunks ----
    ISSUE(va, 0)
    ISSUE(vb, 1)
    PROCESS(va, 0)          // ent row 0 published
    ISSUE(va, 2)
    PROCESS(vb, 1)          // ent row 1 published
    ISSUE(vb, 3)
    WAITROW(0); WAITROW(1);
    WR(0, 96)               // rows 0..95    (ent rows 0,1)
    PROCESS(va, 2)          // ent row 2 published
    WAITROW(2);
    WR(96, 64)              // rows 96..159  (ent rows 1,2)
    PROCESS(vb, 3)          // ent row 3 published
    WAITROW(3);
    WR(160, 96)             // rows 160..255 (ent rows 2,3)

#undef ISSUE
#undef PROCESS
#undef WAITROW
#undef WR
}

extern "C" void kernel_launch(void* const* d_in, const int* in_sizes, int n_in,
                              void* d_out, int out_size, void* d_ws, size_t ws_size,
                              hipStream_t stream) {
    const float* x   = (const float*)d_in[0];
    float*       out = (float*)d_out;
    fused_kernel<<<512, 256, 0, stream>>>(x, out);
}